// Round 12
// baseline (251.681 us; speedup 1.0000x reference)
//
#include <hip/hip_runtime.h>
#include <hip/hip_fp8.h>

#define M_DIM 16384
#define N_DIM 4096
#define K_DIM 2048
#define NT64  (K_DIM / 64)     // 32 K-tiles of 64
#define NSB   (K_DIM / 64)     // k-sub-blocks per 32-row block (32 rows x 64 k each)

typedef float floatx16 __attribute__((ext_vector_type(16)));
typedef int   intx4    __attribute__((ext_vector_type(4)));
typedef int   intx8    __attribute__((ext_vector_type(8)));

__device__ __forceinline__ unsigned char f32_to_fp8(float v) {
    __hip_fp8_e4m3 t(v);
    return t.__x;
}

__device__ __forceinline__ float fp8_roundtrip(float v) {
    __hip_fp8_e4m3 t(v);
    return (float)t;
}

// async global->LDS, 16B per lane. LDS dest is wave-uniform base + lane*16.
__device__ __forceinline__ void async16(const void* g, void* l) {
    __builtin_amdgcn_global_load_lds((__attribute__((address_space(1))) void*)g,
                                     (__attribute__((address_space(3))) void*)l,
                                     16, 0, 0);
}

// read a lane-linear 32B fragment: two 16B halves 1024B apart (zero-conflict)
__device__ __forceinline__ intx8 ld8(const unsigned char* p) {
    intx4 lo = *(const intx4*)(p);
    intx4 hi = *(const intx4*)(p + 1024);
    return __builtin_shufflevector(lo, hi, 0, 1, 2, 3, 4, 5, 6, 7);
}

// ---- quantize + pack into 32x32x64-MFMA fragment order (unchanged) ----
// Sub-block = 32 rows x 64 k = 2048 B. qX[rb][kt][2048], rb = m>>5, kt = k>>6.
// Lane l (r = l&31, h = l>>5) owns k-window kt*64 + h*32 .. +31, stored as
// bytes 0-15 at l*16 and bytes 16-31 at 1024 + l*16. Staging is identity
// (lane-linear 16B), fragment reads are lane-linear ds_read_b128 -> zero bank
// conflicts. A and B share this map, so any hardware-internal k permutation
// cancels in the MFMA dot product.
__global__ void quant_pack_kernel(const float* __restrict__ in,
                                  unsigned char* __restrict__ out,
                                  const float* __restrict__ sp) {
    const int p = blockIdx.x * blockDim.x + threadIdx.x;  // one 16B packed chunk
    const float s = sp ? *sp : 1.0f;
    const int c    = p & 127;            // chunk within sub-block
    const int sb   = p >> 7;
    const int kt   = sb & (NSB - 1);
    const int rb   = sb >> 5;            // log2(NSB) = 5
    const int half = c >> 6;
    const int l    = c & 63;
    const size_t m = (size_t)rb * 32 + (l & 31);
    const int   k0 = kt * 64 + (l >> 5) * 32 + half * 16;
    const float* src = in + m * K_DIM + k0;
    float f[16];
    *(float4*)(f)      = *(const float4*)(src);
    *(float4*)(f + 4)  = *(const float4*)(src + 4);
    *(float4*)(f + 8)  = *(const float4*)(src + 8);
    *(float4*)(f + 12) = *(const float4*)(src + 12);
    unsigned long long lo = 0, hi = 0;
#pragma unroll
    for (int j = 0; j < 8; ++j) {
        float v0 = fminf(fmaxf(f[j] * s, -0.5f), 0.5f);
        float v1 = fminf(fmaxf(f[j + 8] * s, -0.5f), 0.5f);
        lo |= (unsigned long long)f32_to_fp8(v0) << (8 * j);
        hi |= (unsigned long long)f32_to_fp8(v1) << (8 * j);
    }
    unsigned long long* dst = (unsigned long long*)(out + (size_t)p * 16);
    dst[0] = lo;
    dst[1] = hi;
}

#define MF(A_, B_, C_) (C_) = __builtin_amdgcn_mfma_scale_f32_32x32x64_f8f6f4( \
        (A_), (B_), (C_), 0, 0, 0, 0x7F7F7F7F, 0, 0x7F7F7F7F)

// ---- MX-fp8 GEMM: 128x128 tile, BK=64, 4 waves (2x2, 64x64/wave) ----
// SMALL-BLOCK / HIGH-TLP variant: 32 KB LDS + <=128 VGPR -> 4 independent
// blocks per CU (4 waves/SIMD from 4 different barrier domains). Simple
// 2-barrier loop per K-tile; cross-BLOCK slip provides the MFMA<->LDS overlap
// (m114 mechanism) that phase-locked single-block schedules could not.
// Scales fixed at e8m0 1.0 (0x7F) -> numerically identical to plain fp8 GEMM.
__global__ __launch_bounds__(256, 4) void gemm_fp8_kernel(
        const unsigned char* __restrict__ qA, const unsigned char* __restrict__ qB,
        const float* __restrict__ bias, float* __restrict__ out) {
    __shared__ unsigned char Al[2][4 * 2048];   // 2 stages x 8 KB (128 rows x 64 k)
    __shared__ unsigned char Bl[2][4 * 2048];   // 2 stages x 8 KB

    const int tid  = threadIdx.x;
    const int lane = tid & 63;
    const int wid  = tid >> 6;           // 0..3

    // XCD-aware swizzle: 4096 blocks % 8 == 0 -> bijective simple form.
    // bm varies fastest within an XCD chunk -> 32 CUs of an XCD share one
    // bn -> shared 256 KB B panel stays L2-resident.
    const int cpx = gridDim.x >> 3;
    const int swz = (blockIdx.x & 7) * cpx + (blockIdx.x >> 3);
    const int bm = swz & 127;            // M/128 = 128 tiles
    const int bn = swz >> 7;             // N/128 = 32 tiles

    // staging: wave wid stages A sub-block wid and B sub-block wid each tile
    // (2 + 2 async16). Row-block stride = NSB*2048 = 64 KB.
    const unsigned char* gAw = qA + ((size_t)(bm * 4 + wid) << 16) + (lane << 4);
    const unsigned char* gBw = qB + ((size_t)(bn * 4 + wid) << 16) + (lane << 4);

    // compute: wave (g = wid>>1, cc = wid&1) owns a 64x64 output sub-tile
    const int g  = wid >> 1;
    const int cc = wid & 1;

    floatx16 acc[2][2] = {};             // 2x2 of 32x32 = 64 VGPR

    // ---- prologue: stage tile 0 into buffer 0 ----
    async16(gAw,        &Al[0][wid * 2048]);
    async16(gAw + 1024, &Al[0][wid * 2048 + 1024]);
    async16(gBw,        &Bl[0][wid * 2048]);
    async16(gBw + 1024, &Bl[0][wid * 2048 + 1024]);
    __syncthreads();

    int cur = 0;
    for (int t = 0; t < NT64; ++t) {
        const int nb = cur ^ 1;
        // stage next tile into the other buffer (drained by the tile-end sync)
        if (t + 1 < NT64) {
            const size_t go = (size_t)(t + 1) * 2048;
            async16(gAw + go,        &Al[nb][wid * 2048]);
            async16(gAw + go + 1024, &Al[nb][wid * 2048 + 1024]);
            async16(gBw + go,        &Bl[nb][wid * 2048]);
            async16(gBw + go + 1024, &Bl[nb][wid * 2048 + 1024]);
        }
        // fragment reads (lane-linear, zero-conflict)
        intx8 a0 = ld8(&Al[cur][(2 * g + 0) * 2048 + (lane << 4)]);
        intx8 a1 = ld8(&Al[cur][(2 * g + 1) * 2048 + (lane << 4)]);
        intx8 b0 = ld8(&Bl[cur][(2 * cc + 0) * 2048 + (lane << 4)]);
        intx8 b1 = ld8(&Bl[cur][(2 * cc + 1) * 2048 + (lane << 4)]);
        // 4 independent MFMAs
        __builtin_amdgcn_s_setprio(1);
        MF(a0, b0, acc[0][0]); MF(a0, b1, acc[0][1]);
        MF(a1, b0, acc[1][0]); MF(a1, b1, acc[1][1]);
        __builtin_amdgcn_s_setprio(0);
        // tile boundary: drain staging + swap buffers (intra-block only;
        // the other 3 blocks on this CU keep their pipes busy meanwhile)
        __syncthreads();
        cur = nb;
    }

    // epilogue: 32x32 C/D layout col=lane&31, row=(r&3)+8*(r>>2)+4*(lane>>5)
    const int orow_b = bm * 128 + g * 64 + ((lane >> 5) << 2);
    const int ocol_b = bn * 128 + cc * 64 + (lane & 31);
#pragma unroll
    for (int ni = 0; ni < 2; ++ni) {
        const int oc = ocol_b + ni * 32;
        const float bv = bias[oc];
#pragma unroll
        for (int mi = 0; mi < 2; ++mi) {
#pragma unroll
            for (int r = 0; r < 16; ++r) {
                const int orow = orow_b + mi * 32 + (r & 3) + 8 * (r >> 2);
                out[(size_t)orow * N_DIM + oc] = fp8_roundtrip(acc[mi][ni][r]) + bv;
            }
        }
    }
}

// ---- fallback (only if ws too small): 1 thread per output, exact fp32 accumulation ----
__global__ void naive_kernel(const float* __restrict__ x, const float* __restrict__ w,
                             const float* __restrict__ bias, const float* __restrict__ sp,
                             float* __restrict__ out) {
    const int ncol = blockIdx.x * blockDim.x + threadIdx.x;
    const int m = blockIdx.y;
    const float s = *sp;
    float acc = 0.f;
    for (int k = 0; k < K_DIM; ++k) {
        float q = fp8_roundtrip(fminf(fmaxf(x[(size_t)m * K_DIM + k] * s, -0.5f), 0.5f));
        acc += q * w[(size_t)ncol * K_DIM + k];
    }
    out[(size_t)m * N_DIM + ncol] = fp8_roundtrip(acc) + bias[ncol];
}

extern "C" void kernel_launch(void* const* d_in, const int* in_sizes, int n_in,
                              void* d_out, int out_size, void* d_ws, size_t ws_size,
                              hipStream_t stream) {
    const float* x     = (const float*)d_in[0];
    const float* w     = (const float*)d_in[1];
    const float* bias  = (const float*)d_in[2];
    const float* scale = (const float*)d_in[3];
    float* out = (float*)d_out;

    const size_t needA = (size_t)M_DIM * K_DIM;   // 33.5 MB fp8
    const size_t needB = (size_t)N_DIM * K_DIM;   //  8.4 MB fp8

    if (ws_size >= needA + needB) {
        unsigned char* qA = (unsigned char*)d_ws;
        unsigned char* qB = qA + needA;
        quant_pack_kernel<<<(M_DIM * K_DIM / 16) / 256, 256, 0, stream>>>(x, qA, scale);
        quant_pack_kernel<<<(N_DIM * K_DIM / 16) / 256, 256, 0, stream>>>(w, qB, nullptr);
        gemm_fp8_kernel<<<(M_DIM / 128) * (N_DIM / 128), 256, 0, stream>>>(qA, qB, bias, out);
    } else {
        dim3 g(N_DIM / 256, M_DIM);
        naive_kernel<<<g, 256, 0, stream>>>(x, w, bias, scale, out);
    }
}